// Round 5
// baseline (158.112 us; speedup 1.0000x reference)
//
#include <hip/hip_runtime.h>
#include <math.h>

#define SA 20        // alphabet
#define KDIM 2
#define MDIM 2
#define BDIM 512
#define LDIM 512
#define NRATES 512
#define MATW (SA * SA)              // 400 floats per matrix
#define NCH (LDIM * KDIM * SA / 4)  // 5120 float4 chunks per pair

__device__ __forceinline__ float softplusf(float x) {
    return fmaxf(x, 0.0f) + log1pf(expf(-fabsf(x)));
}

// C(row-per-lane regs) = A(regs) * B(LDS 20x20 row-major contiguous 400-float
// block). Same-address float4 reads broadcast, conflict-free.
__device__ __forceinline__ void mmB(float* C, const float* A, const float* Bl) {
    #pragma unroll
    for (int j = 0; j < SA; ++j) C[j] = 0.0f;
    #pragma unroll
    for (int t = 0; t < SA; ++t) {
        const float a = A[t];
        const float4* row = reinterpret_cast<const float4*>(Bl + t * SA);
        #pragma unroll
        for (int q = 0; q < 5; ++q) {
            float4 b = row[q];
            C[4*q+0] = fmaf(a, b.x, C[4*q+0]);
            C[4*q+1] = fmaf(a, b.y, C[4*q+1]);
            C[4*q+2] = fmaf(a, b.z, C[4*q+2]);
            C[4*q+3] = fmaf(a, b.w, C[4*q+3]);
        }
    }
}

__device__ __forceinline__ void stageRow(float* dst, const float* T, int row, bool act) {
    if (act) {
        float4* d4 = reinterpret_cast<float4*>(dst + row * SA);
        #pragma unroll
        for (int q = 0; q < 5; ++q)
            d4[q] = make_float4(T[4*q+0], T[4*q+1], T[4*q+2], T[4*q+3]);
    }
}

__global__ __launch_bounds__(256) void ancprobs_onepass_kernel(
    const int*   __restrict__ seqg,
    const int*   __restrict__ rateIdx,
    const float* __restrict__ tauk,
    const float* __restrict__ Ek,
    const float* __restrict__ eqk,
    float*       __restrict__ out)
{
    __shared__ __align__(16) float sPw[KDIM][6][MATW];  // Qhat^(d+1), d=0..5: 19.2 KB
    __shared__ __align__(16) float sT[2][KDIM][MATW];   // P double-buffer: 6.4 KB
    __shared__ int   sSeq[LDIM];                        // 2 KB
    __shared__ float sn[KDIM];

    const int tid  = threadIdx.x;
    const int mb   = blockIdx.x;        // pair in [0, 1024)
    const int mm   = mb >> 9;           // BDIM = 512
    const int w    = tid >> 6;
    const int lane = tid & 63;

    // uniform per-pair scalars (s_load path), issued early
    const int   ri  = rateIdx[mb];
    const float tau = softplusf(tauk[mm * NRATES + ri]);

    // stage sequence: 128 int4, coalesced
    if (tid < 128)
        reinterpret_cast<int4*>(sSeq)[tid] =
            reinterpret_cast<const int4*>(seqg + (size_t)mb * LDIM)[tid];

    if (w == 0) {
        // wave 0: qmat (both k halves) + Q^2 + Q^3, same-wave LDS chaining
        const int  half = lane >> 5;
        const int  row  = lane & 31;
        const bool act  = row < SA;
        const int  mk   = mm * KDIM + half;
        const int  r0   = act ? row : 0;

        // p = softmax(eqk)
        float e = act ? eqk[mk * SA + row] : -INFINITY;
        float mx = e;
        #pragma unroll
        for (int off = 16; off; off >>= 1) mx = fmaxf(mx, __shfl_xor(mx, off, 32));
        float ex = act ? expf(e - mx) : 0.0f;
        float sm = ex;
        #pragma unroll
        for (int off = 16; off; off >>= 1) sm += __shfl_xor(sm, off, 32);
        float p_i = ex / sm;

        // Qhat row (normalized rate matrix)
        float Q[SA];
        float dg = 0.0f;
        #pragma unroll
        for (int j = 0; j < SA; ++j) {
            float pj = __shfl(p_i, j, 32);
            float e1 = Ek[(mk * SA + r0) * SA + j];
            float e2 = Ek[(mk * SA + j) * SA + r0];
            float r  = (j == row) ? 0.0f : softplusf(0.5f * (e1 + e2));
            float q  = r * pj;
            Q[j] = q;
            dg  += q;
        }
        float t_ = act ? p_i * dg : 0.0f;
        #pragma unroll
        for (int off = 16; off; off >>= 1) t_ += __shfl_xor(t_, off, 32);
        const float inv = 1.0f / fmaxf(t_, 1e-16f);
        #pragma unroll
        for (int j = 0; j < SA; ++j)
            Q[j] = act ? ((j == row) ? -dg * inv : Q[j] * inv) : 0.0f;

        // ||Qhat||_inf
        float rn = 0.0f;
        #pragma unroll
        for (int j = 0; j < SA; ++j) rn += fabsf(Q[j]);
        #pragma unroll
        for (int off = 16; off; off >>= 1) rn = fmaxf(rn, __shfl_xor(rn, off, 32));
        if (act && row == 0) sn[half] = rn;

        stageRow(&sPw[half][0][0], Q, row, act);       // Q^1
        float G2[SA];
        mmB(G2, Q, &sPw[half][0][0]);                  // Q^2 (same-wave LDS RAW ok)
        stageRow(&sPw[half][1][0], G2, row, act);
        float G3[SA];
        mmB(G3, G2, &sPw[half][0][0]);                 // Q^3
        stageRow(&sPw[half][2][0], G3, row, act);
    }
    __syncthreads();

    if (w >= 1) {
        // one parallel round: w1: Q^4=Q2*Q2, w2: Q^5=Q3*Q2, w3: Q^6=Q3*Q3
        const int  half = lane >> 5;
        const int  row  = lane & 31;
        const bool act  = row < SA;
        const int  r0   = act ? row : 0;
        const int  srcA = (w == 1) ? 1 : 2;
        const int  srcB = (w == 3) ? 2 : 1;
        const int  dst  = w + 2;

        float A[SA];
        const float4* a4 = reinterpret_cast<const float4*>(&sPw[half][srcA][0] + r0 * SA);
        #pragma unroll
        for (int q = 0; q < 5; ++q) {
            float4 v = a4[q];
            A[4*q+0] = v.x; A[4*q+1] = v.y; A[4*q+2] = v.z; A[4*q+3] = v.w;
        }
        float G[SA];
        mmB(G, A, &sPw[half][srcB][0]);
        stageRow(&sPw[half][dst][0], G, row, act);
    }
    __syncthreads();

    // scaling counts per k
    const float n0 = sn[0], n1 = sn[1];
    int s0 = 0, s1 = 0;
    {
        float y0 = tau * n0;
        if (y0 > 1.0f) s0 = (int)ceilf(log2f(y0));
        s0 = min(max(s0, 0), 30);
        float y1 = tau * n1;
        if (y1 > 1.0f) s1 = (int)ceilf(log2f(y1));
        s1 = min(max(s1, 0), 30);
    }
    float cf0[6], cf1[6];
    {
        float x = tau * exp2f(-(float)s0);
        cf0[0] = x;             cf0[1] = cf0[0] * x * 0.5f;
        cf0[2] = cf0[1] * x * (1.0f/3.0f); cf0[3] = cf0[2] * x * 0.25f;
        cf0[4] = cf0[3] * x * 0.2f;        cf0[5] = cf0[4] * x * (1.0f/6.0f);
        x = tau * exp2f(-(float)s1);
        cf1[0] = x;             cf1[1] = cf1[0] * x * 0.5f;
        cf1[2] = cf1[1] * x * (1.0f/3.0f); cf1[3] = cf1[2] * x * 0.25f;
        cf1[4] = cf1[3] * x * 0.2f;        cf1[5] = cf1[4] * x * (1.0f/6.0f);
    }

    // per-element combo: T = I + sum_{d=1..6} cf[d] * Qhat^d  (800 elements)
    #pragma unroll
    for (int ei = 0; ei < 4; ++ei) {
        const int e = tid + ei * 256;
        if (ei < 3 || tid < 32) {
            const int kk  = (e >= MATW) ? 1 : 0;
            const int idx = e - kk * MATW;
            const float* cf = kk ? cf1 : cf0;
            float acc = (idx % 21 == 0) ? 1.0f : 0.0f;   // diagonal of I
            #pragma unroll
            for (int d = 0; d < 6; ++d)
                acc = fmaf(cf[d], sPw[kk][d][idx], acc);
            sT[0][kk][idx] = acc;
        }
    }
    __syncthreads();

    // rare squarings (block-uniform trip count)
    int buf = 0;
    const int smax = max(s0, s1);
    if (smax > 0) {
        for (int it = 0; it < smax; ++it) {
            #pragma unroll
            for (int ei = 0; ei < 4; ++ei) {
                const int e = tid + ei * 256;
                if (ei < 3 || tid < 32) {
                    const int kk  = (e >= MATW) ? 1 : 0;
                    const int idx = e - kk * MATW;
                    const int r   = idx / SA;
                    const int c   = idx - r * SA;
                    const int sk  = kk ? s1 : s0;
                    float acc;
                    if (it < sk) {
                        acc = 0.0f;
                        const float* Tm = &sT[buf][kk][0];
                        #pragma unroll
                        for (int t = 0; t < SA; ++t)
                            acc = fmaf(Tm[r * SA + t], Tm[t * SA + c], acc);
                    } else {
                        acc = sT[buf][kk][idx];
                    }
                    sT[buf ^ 1][kk][idx] = acc;
                }
            }
            __syncthreads();
            buf ^= 1;
        }
    }

    // gather + coalesced stream: out[mb, l, kk, :] = P[kk][seq[l]][:]
    const float4* pv = reinterpret_cast<const float4*>(&sT[buf][0][0]);
    float4* o4 = reinterpret_cast<float4*>(out) + (size_t)mb * NCH;
    #pragma unroll 1
    for (int g = 0; g < 4; ++g) {
        int    cc[5];
        float4 v[5];
        #pragma unroll
        for (int i = 0; i < 5; ++i) {
            const int c  = tid + (g * 5 + i) * 256;
            const int l  = c / 10;
            const int ch = c - l * 10;
            const int kk = (ch >= 5) ? 1 : 0;
            const int c4 = ch - kk * 5;
            const int sq = sSeq[l];
            cc[i] = c;
            v[i]  = pv[kk * 100 + sq * 5 + c4];
        }
        #pragma unroll
        for (int i = 0; i < 5; ++i) o4[cc[i]] = v[i];
    }
}

extern "C" void kernel_launch(void* const* d_in, const int* in_sizes, int n_in,
                              void* d_out, int out_size, void* d_ws, size_t ws_size,
                              hipStream_t stream) {
    const int*   seq  = (const int*)d_in[0];
    const int*   ridx = (const int*)d_in[1];
    const float* tauk = (const float*)d_in[2];
    const float* Ek   = (const float*)d_in[3];
    const float* eqk  = (const float*)d_in[4];
    float* out = (float*)d_out;

    ancprobs_onepass_kernel<<<MDIM * BDIM, 256, 0, stream>>>(
        seq, ridx, tauk, Ek, eqk, out);
}

// Round 6
// 118.680 us; speedup vs baseline: 1.3323x; 1.3323x over previous
//
#include <hip/hip_runtime.h>
#include <math.h>

#define SA 20        // alphabet
#define KDIM 2
#define MDIM 2
#define BDIM 512
#define LDIM 512
#define NRATES 512
#define MATW (SA * SA)              // 400 floats per matrix
#define NCH (LDIM * KDIM * SA / 4)  // 5120 float4 chunks per (m,b) pair
#define SPLIT 4                     // gather blocks per pair
#define GCH (NCH / SPLIT)           // 1280 chunks per gather block
#define LSLICE (LDIM / SPLIT)       // 128 l-positions per gather block

__device__ __forceinline__ float softplusf(float x) {
    return fmaxf(x, 0.0f) + log1pf(expf(-fabsf(x)));
}

// C(row-per-lane regs) = A(regs) * B(LDS 20x20 row-major contiguous 400-float
// block). Same-address float4 reads broadcast, conflict-free.
__device__ __forceinline__ void mmB(float* C, const float* A, const float* Bl) {
    #pragma unroll
    for (int j = 0; j < SA; ++j) C[j] = 0.0f;
    #pragma unroll
    for (int t = 0; t < SA; ++t) {
        const float a = A[t];
        const float4* row = reinterpret_cast<const float4*>(Bl + t * SA);
        #pragma unroll
        for (int q = 0; q < 5; ++q) {
            float4 b = row[q];
            C[4*q+0] = fmaf(a, b.x, C[4*q+0]);
            C[4*q+1] = fmaf(a, b.y, C[4*q+1]);
            C[4*q+2] = fmaf(a, b.z, C[4*q+2]);
            C[4*q+3] = fmaf(a, b.w, C[4*q+3]);
        }
    }
}

__device__ __forceinline__ void stageRow(float* dst, const float* T, int row, bool act) {
    if (act) {
        float4* d4 = reinterpret_cast<float4*>(dst + row * SA);
        #pragma unroll
        for (int q = 0; q < 5; ++q)
            d4[q] = make_float4(T[4*q+0], T[4*q+1], T[4*q+2], T[4*q+3]);
    }
}

// ---------------- Kernel A: fused qmat + expm, one (m,b) pair per block -----
// 64-thread blocks: register pressure here cannot hurt the store stream.
__global__ __launch_bounds__(64) void expm_kernel(
    const int*   __restrict__ rateIdx,
    const float* __restrict__ tauk,
    const float* __restrict__ Ek,
    const float* __restrict__ eqk,
    float*       __restrict__ Pg)      // (1024, 2, 20, 20)
{
    __shared__ float sStage[KDIM * MATW];

    const int lane = threadIdx.x;       // one wave
    const int mb   = blockIdx.x;        // pair in [0, 1024)
    const int mm   = mb >> 9;           // BDIM = 512

    const int  half = lane >> 5;        // which k
    const int  row  = lane & 31;
    const bool act  = row < SA;
    const int  mk   = mm * KDIM + half;
    const int  r0   = act ? row : 0;
    float* stage = sStage + half * MATW;

    // p = softmax(eqk)
    float e = act ? eqk[mk * SA + row] : -INFINITY;
    float mx = e;
    #pragma unroll
    for (int off = 16; off; off >>= 1) mx = fmaxf(mx, __shfl_xor(mx, off, 32));
    float ex = act ? expf(e - mx) : 0.0f;
    float sm = ex;
    #pragma unroll
    for (int off = 16; off; off >>= 1) sm += __shfl_xor(sm, off, 32);
    float p_i = ex / sm;

    // R = softplus(sym(Ek)) off-diag; Q = R*p - diag(rowsum); normalize by mue
    float A[SA];
    float dg = 0.0f;
    #pragma unroll
    for (int j = 0; j < SA; ++j) {
        float pj = __shfl(p_i, j, 32);
        float e1 = Ek[(mk * SA + r0) * SA + j];
        float e2 = Ek[(mk * SA + j) * SA + r0];
        float r  = (j == row) ? 0.0f : softplusf(0.5f * (e1 + e2));
        float q  = r * pj;
        A[j] = q;
        dg  += q;
    }
    float t_ = act ? p_i * dg : 0.0f;
    #pragma unroll
    for (int off = 16; off; off >>= 1) t_ += __shfl_xor(t_, off, 32);
    const float inv = 1.0f / fmaxf(t_, 1e-16f);

    const float tau = softplusf(tauk[mm * NRATES + rateIdx[mb]]);
    const float sc  = tau * inv;
    #pragma unroll
    for (int j = 0; j < SA; ++j)
        A[j] = act ? ((j == row) ? -dg * sc : A[j] * sc) : 0.0f;

    // scaling: s = ceil(log2(||A||inf)), theta = 1.0
    float rn = 0.0f;
    #pragma unroll
    for (int j = 0; j < SA; ++j) rn += fabsf(A[j]);
    #pragma unroll
    for (int off = 16; off; off >>= 1) rn = fmaxf(rn, __shfl_xor(rn, off, 32));
    int s = 0;
    if (rn > 1.0f) s = (int)ceilf(log2f(rn));
    if (s < 0) s = 0;
    if (s > 30) s = 30;
    const float scale = exp2f((float)(-s));
    #pragma unroll
    for (int j = 0; j < SA; ++j) A[j] *= scale;
    const int smax = max(s, __shfl_xor(s, 32, 64));

    // degree-6 Paterson-Stockmeyer Taylor: 3 matmuls
    float A2[SA], A3[SA], T[SA];
    stageRow(stage, A, row, act);
    mmB(A2, A, stage);
    mmB(A3, A2, stage);
    #pragma unroll
    for (int j = 0; j < SA; ++j) {
        float id = (j == row) ? 1.0f : 0.0f;
        T[j] = (1.0f/6.0f)*id + (1.0f/24.0f)*A[j] + (1.0f/120.0f)*A2[j] + (1.0f/720.0f)*A3[j];
    }
    stageRow(stage, T, row, act);      // stage B1
    {
        float P1[SA];
        mmB(P1, A3, stage);
        #pragma unroll
        for (int j = 0; j < SA; ++j) {
            float id = (j == row) ? 1.0f : 0.0f;
            T[j] = P1[j] + id + A[j] + 0.5f * A2[j];
        }
    }
    for (int it = 0; it < smax; ++it) {
        stageRow(stage, T, row, act);
        float Tn[SA];
        mmB(Tn, T, stage);
        const bool doit = it < s;
        #pragma unroll
        for (int j = 0; j < SA; ++j) T[j] = doit ? Tn[j] : T[j];
    }

    // write P rows: Pg[mb, half, row, :]
    if (act) {
        float4* d4 = reinterpret_cast<float4*>(Pg + ((size_t)mb * KDIM + half) * MATW + row * SA);
        #pragma unroll
        for (int q = 0; q < 5; ++q)
            d4[q] = make_float4(T[4*q+0], T[4*q+1], T[4*q+2], T[4*q+3]);
    }
}

// ---------------- Kernel B: minimal-register LDS gather + streamer ----------
// 4096 blocks x 256 thr; 5.3 KB LDS, ~30 VGPR -> 8 blocks/CU = 32 waves/CU.
__global__ __launch_bounds__(256, 8) void gather_kernel(
    const int*   __restrict__ seqg,
    const float* __restrict__ Pg,
    float*       __restrict__ out)
{
    __shared__ float4 sP4[KDIM * SA * 5];   // 200 float4 = 3.2 KB
    __shared__ int    sSeq[LSLICE];         // 128 ints

    const int tid = threadIdx.x;
    const int mb  = blockIdx.x >> 2;        // pair
    const int qq  = blockIdx.x & 3;         // quarter of the pair's L range

    // stage P tile (200 coalesced float4) and this quarter's 128 seq ints
    if (tid < 200) {
        sP4[tid] = reinterpret_cast<const float4*>(Pg + (size_t)mb * KDIM * MATW)[tid];
    } else if (tid >= 224) {
        reinterpret_cast<int4*>(sSeq)[tid - 224] =
            reinterpret_cast<const int4*>(seqg + (size_t)mb * LDIM + qq * LSLICE)[tid - 224];
    }
    __syncthreads();

    float4* o4 = reinterpret_cast<float4*>(out) + (size_t)mb * NCH + qq * GCH;
    #pragma unroll
    for (int i = 0; i < 5; ++i) {
        const int c  = tid + i * 256;       // 0..1279 within quarter
        const int l  = c / 10;              // local l position
        const int ch = c - l * 10;
        const int kk = (ch >= 5) ? 1 : 0;
        const int c4 = ch - kk * 5;
        o4[c] = sP4[kk * 100 + sSeq[l] * 5 + c4];
    }
}

extern "C" void kernel_launch(void* const* d_in, const int* in_sizes, int n_in,
                              void* d_out, int out_size, void* d_ws, size_t ws_size,
                              hipStream_t stream) {
    const int*   seq  = (const int*)d_in[0];
    const int*   ridx = (const int*)d_in[1];
    const float* tauk = (const float*)d_in[2];
    const float* Ek   = (const float*)d_in[3];
    const float* eqk  = (const float*)d_in[4];
    float* out = (float*)d_out;
    float* Pg  = (float*)d_ws;   // 1024*2*400 floats = 3.2 MB

    expm_kernel<<<MDIM * BDIM, 64, 0, stream>>>(ridx, tauk, Ek, eqk, Pg);
    gather_kernel<<<MDIM * BDIM * SPLIT, 256, 0, stream>>>(seq, Pg, out);
}

// Round 7
// 114.119 us; speedup vs baseline: 1.3855x; 1.0400x over previous
//
#include <hip/hip_runtime.h>
#include <math.h>

#define SA 20
#define KDIM 2
#define MDIM 2
#define BDIM 512
#define LDIM 512
#define NRATES 512
#define MATW (SA * SA)               // 400
#define NEL (KDIM * MATW)            // 800 elements across both k
#define SPLIT 2                      // blocks per (m,b) pair
#define NCH (LDIM * KDIM * SA / 4)   // 5120 float4 per pair
#define GCH (NCH / SPLIT)            // 2560 float4 per block
#define LSLICE (LDIM / SPLIT)        // 256 l-positions per block
#define GITER (GCH / 256)            // 10 stores per thread

__device__ __forceinline__ float softplusf(float x) {
    return fmaxf(x, 0.0f) + log1pf(expf(-fabsf(x)));
}

__global__ __launch_bounds__(256) void ancprobs_lean_kernel(
    const int*   __restrict__ seqg,
    const int*   __restrict__ rateIdx,
    const float* __restrict__ tauk,
    const float* __restrict__ Ek,
    const float* __restrict__ eqk,
    float*       __restrict__ out)
{
    __shared__ __align__(16) float sA[NEL];    // raw Q -> scaled A
    __shared__ __align__(16) float sB1[NEL];   // Ek staging -> Horner ping
    __shared__ __align__(16) float sB2[NEL];   // Horner pong
    __shared__ int   sSeq[LSLICE];
    __shared__ float sp[KDIM * SA];            // softmax p
    __shared__ float sd[KDIM * SA];            // row sums
    __shared__ float sFac[KDIM];               // tau * 2^-s / mue
    __shared__ int   sS[KDIM];                 // squaring counts
    __shared__ float sTau;

    const int tid = threadIdx.x;
    const int mb  = blockIdx.x >> 1;     // pair in [0,1024)
    const int qq  = blockIdx.x & 1;      // which half of L
    const int mm  = mb >> 9;             // BDIM = 512

    // ---- stage: seq slice (64 int4), Ek both k (200 float4), eqk (40 f), tau
    if (tid < 64)
        reinterpret_cast<int4*>(sSeq)[tid] =
            reinterpret_cast<const int4*>(seqg + (size_t)mb * LDIM + qq * LSLICE)[tid];
    if (tid < 200)
        reinterpret_cast<float4*>(sB1)[tid] =
            reinterpret_cast<const float4*>(Ek + (size_t)mm * NEL)[tid];
    if (tid >= 200 && tid < 240)
        sp[tid - 200] = eqk[mm * KDIM * SA + (tid - 200)];   // borrow sp for raw eqk
    if (tid == 255)
        sTau = softplusf(tauk[mm * NRATES + rateIdx[mb]]);
    __syncthreads();

    // ---- softmax p per k (one wave; lanes 0..31 -> k=0, 32..63 -> k=1)
    if (tid < 64) {
        const int  half = tid >> 5;
        const int  row  = tid & 31;
        const bool act  = row < SA;
        float e = act ? sp[half * SA + row] : -INFINITY;
        float mx = e;
        #pragma unroll
        for (int off = 16; off; off >>= 1) mx = fmaxf(mx, __shfl_xor(mx, off, 32));
        float ex = act ? expf(e - mx) : 0.0f;
        float sm = ex;
        #pragma unroll
        for (int off = 16; off; off >>= 1) sm += __shfl_xor(sm, off, 32);
        if (act) sd[half * SA + row] = ex / sm;   // park p in sd temporarily
    }
    __syncthreads();

    // ---- R*p element-parallel: off-diag raw q into sA
    for (int e = tid; e < NEL; e += 256) {
        const int kk  = (e >= MATW) ? 1 : 0;
        const int idx = e - kk * MATW;
        const int r   = idx / SA;
        const int c   = idx - r * SA;
        float v = 0.0f;
        if (r != c) {
            float e1 = sB1[kk * MATW + r * SA + c];
            float e2 = sB1[kk * MATW + c * SA + r];
            v = softplusf(0.5f * (e1 + e2)) * sd[kk * SA + c];
        }
        sA[e] = v;
    }
    __syncthreads();
    // copy p out of sd before overwriting (one wave)
    if (tid < 40) sp[tid] = sd[tid];
    __syncthreads();

    // ---- row sums, mue, scaling factor per k (one wave)
    if (tid < 64) {
        const int  half = tid >> 5;
        const int  row  = tid & 31;
        const bool act  = row < SA;
        float dg = 0.0f;
        if (act) {
            const float* rp = sA + half * MATW + row * SA;
            #pragma unroll
            for (int c = 0; c < SA; ++c) dg += rp[c];
        }
        float p_i = act ? sp[half * SA + row] : 0.0f;
        float t_ = p_i * dg;
        #pragma unroll
        for (int off = 16; off; off >>= 1) t_ += __shfl_xor(t_, off, 32);
        const float inv = 1.0f / fmaxf(t_, 1e-16f);
        float rm = act ? dg : 0.0f;
        #pragma unroll
        for (int off = 16; off; off >>= 1) rm = fmaxf(rm, __shfl_xor(rm, off, 32));
        const float tau = sTau;
        const float n   = tau * inv * 2.0f * rm;    // ||tau*Qhat||_inf
        int s = 0;
        if (n > 1.0f) s = (int)ceilf(log2f(n));
        s = min(max(s, 0), 30);
        if (act) sd[half * SA + row] = dg;
        if (row == 0) {
            sFac[half] = tau * inv * exp2f(-(float)s);
            sS[half]   = s;
        }
    }
    __syncthreads();

    // ---- finalize A (diag, scale) + innermost Horner term U0 = I + A/6
    for (int e = tid; e < NEL; e += 256) {
        const int kk  = (e >= MATW) ? 1 : 0;
        const int idx = e - kk * MATW;
        const int r   = idx / SA;
        const int c   = idx - r * SA;
        float a = ((r == c) ? -sd[kk * SA + r] : sA[e]) * sFac[kk];
        sA[e]  = a;
        sB1[e] = ((r == c) ? 1.0f : 0.0f) + a * (1.0f / 6.0f);
    }
    __syncthreads();

    // ---- Horner: U <- I + (A*U)/d for d = 5..1 (5 element-parallel matmuls)
    float* cur = sB1;
    float* nxt = sB2;
    #pragma unroll
    for (int d = 5; d >= 1; --d) {
        const float rd = 1.0f / (float)d;
        for (int e = tid; e < NEL; e += 256) {
            const int kk  = (e >= MATW) ? 1 : 0;
            const int idx = e - kk * MATW;
            const int r   = idx / SA;
            const int c   = idx - r * SA;
            const float* ar = sA  + kk * MATW + r * SA;
            const float* uc = cur + kk * MATW + c;
            float acc = 0.0f;
            #pragma unroll
            for (int t = 0; t < SA; ++t)
                acc = fmaf(ar[t], uc[t * SA], acc);
            nxt[e] = ((r == c) ? 1.0f : 0.0f) + acc * rd;
        }
        __syncthreads();
        float* tmp = cur; cur = nxt; nxt = tmp;
    }

    // ---- rare squarings (block-uniform trip count; per-k predicate)
    const int s0 = sS[0], s1 = sS[1];
    const int smax = max(s0, s1);
    for (int it = 0; it < smax; ++it) {
        for (int e = tid; e < NEL; e += 256) {
            const int kk  = (e >= MATW) ? 1 : 0;
            const int idx = e - kk * MATW;
            const int r   = idx / SA;
            const int c   = idx - r * SA;
            const int sk  = kk ? s1 : s0;
            float acc;
            if (it < sk) {
                const float* tr = cur + kk * MATW + r * SA;
                const float* tc = cur + kk * MATW + c;
                acc = 0.0f;
                #pragma unroll
                for (int t = 0; t < SA; ++t)
                    acc = fmaf(tr[t], tc[t * SA], acc);
            } else {
                acc = cur[e];
            }
            nxt[e] = acc;
        }
        __syncthreads();
        float* tmp = cur; cur = nxt; nxt = tmp;
    }

    // ---- gather + coalesced store: out[mb, l, kk, :] = P[kk][seq[l]][:]
    const float4* pv = reinterpret_cast<const float4*>(cur);
    float4* o4 = reinterpret_cast<float4*>(out) + (size_t)mb * NCH + (size_t)qq * GCH;
    #pragma unroll
    for (int i = 0; i < GITER; ++i) {
        const int c  = tid + i * 256;      // 0..2559
        const int l  = c / 10;
        const int ch = c - l * 10;
        const int kk = (ch >= 5) ? 1 : 0;
        const int c4 = ch - kk * 5;
        o4[c] = pv[kk * 100 + sSeq[l] * 5 + c4];
    }
}

extern "C" void kernel_launch(void* const* d_in, const int* in_sizes, int n_in,
                              void* d_out, int out_size, void* d_ws, size_t ws_size,
                              hipStream_t stream) {
    const int*   seq  = (const int*)d_in[0];
    const int*   ridx = (const int*)d_in[1];
    const float* tauk = (const float*)d_in[2];
    const float* Ek   = (const float*)d_in[3];
    const float* eqk  = (const float*)d_in[4];
    float* out = (float*)d_out;

    ancprobs_lean_kernel<<<MDIM * BDIM * SPLIT, 256, 0, stream>>>(
        seq, ridx, tauk, Ek, eqk, out);
}